// Round 6
// baseline (252.524 us; speedup 1.0000x reference)
//
#include <hip/hip_runtime.h>
#include <math.h>

#define T_OBS 256
#define NY 128
#define NITER 150

typedef __fp16 half2_t __attribute__((ext_vector_type(2)));

// ---- gfx9/CDNA DPP wave64 reduction: row_shr 1,2,4,8 + bcast15 + bcast31 ----
#define DPP_ROW_SHR1 0x111
#define DPP_ROW_SHR2 0x112
#define DPP_ROW_SHR4 0x114
#define DPP_ROW_SHR8 0x118
#define DPP_BCAST15  0x142
#define DPP_BCAST31  0x143
#define DPP_QUAD_X1  0xB1   // quad_perm [1,0,3,2]

#define DPP_ADD_F32(x, ctrl) \
    (x) += __int_as_float(__builtin_amdgcn_update_dpp(0, __float_as_int(x), (ctrl), 0xf, 0xf, true))

__device__ __forceinline__ void wave_sum2(float& a, float& b) {
    DPP_ADD_F32(a, DPP_ROW_SHR1); DPP_ADD_F32(b, DPP_ROW_SHR1);
    DPP_ADD_F32(a, DPP_ROW_SHR2); DPP_ADD_F32(b, DPP_ROW_SHR2);
    DPP_ADD_F32(a, DPP_ROW_SHR4); DPP_ADD_F32(b, DPP_ROW_SHR4);
    DPP_ADD_F32(a, DPP_ROW_SHR8); DPP_ADD_F32(b, DPP_ROW_SHR8);
    DPP_ADD_F32(a, DPP_BCAST15);  DPP_ADD_F32(b, DPP_BCAST15);
    DPP_ADD_F32(a, DPP_BCAST31);  DPP_ADD_F32(b, DPP_BCAST31);
    a = __int_as_float(__builtin_amdgcn_readlane(__float_as_int(a), 63));
    b = __int_as_float(__builtin_amdgcn_readlane(__float_as_int(b), 63));
}

__device__ __forceinline__ unsigned rlu(unsigned x, int l) {
    return (unsigned)__builtin_amdgcn_readlane((int)x, l);
}
__device__ __forceinline__ unsigned h2u(half2_t h) {
    return __builtin_bit_cast(unsigned, h);
}
__device__ __forceinline__ half2_t u2h(unsigned u) {
    return __builtin_bit_cast(half2_t, u);
}
__device__ __forceinline__ float dot2u(unsigned a, unsigned b, float c) {
#if __has_builtin(__builtin_amdgcn_fdot2)
    return __builtin_amdgcn_fdot2(u2h(a), u2h(b), c, false);
#else
    half2_t ha = u2h(a), hb = u2h(b);
    return fmaf((float)ha.y, (float)hb.y, fmaf((float)ha.x, (float)hb.x, c));
#endif
}

// ---- kernel 1: Y_hat = X W^T + b ; ep = Y - Y_hat, emitted in two f16 layouts ----
// block handles rows t0=2*blk, t0+1; 128 threads = one output col each.
__global__ __launch_bounds__(128)
void pred_kernel(const float* __restrict__ X, const float* __restrict__ Y,
                 const float* __restrict__ W, const float* __restrict__ bb,
                 float* __restrict__ yhat, __fp16* __restrict__ ep_row,
                 unsigned* __restrict__ ep_cp) {
    __shared__ float xrow[128];               // rows t0,t0+1 of X (contiguous)
    const int blk = blockIdx.x;               // 0..127
    const int j   = threadIdx.x;              // 0..127
    const int t0  = blk << 1;
    xrow[j] = X[t0 * 64 + j];
    __syncthreads();
    const float* wr = W + j * 64;
    float a0 = 0.f, a1 = 0.f;
#pragma unroll
    for (int x = 0; x < 64; ++x) {
        const float w = wr[x];
        a0 = fmaf(xrow[x],      w, a0);
        a1 = fmaf(xrow[64 + x], w, a1);
    }
    const float yh0 = a0 + bb[j];
    const float yh1 = a1 + bb[j];
    yhat[t0 * NY + j]       = yh0;
    yhat[(t0 + 1) * NY + j] = yh1;
    const float e0 = Y[t0 * NY + j] - yh0;
    const float e1 = Y[(t0 + 1) * NY + j] - yh1;
    ep_row[t0 * NY + j]       = (__fp16)e0;
    ep_row[(t0 + 1) * NY + j] = (__fp16)e1;
    // col-pair layout: ep_cp[j*128 + blk] = (ep[2blk][j], ep[2blk+1][j])
    ep_cp[j * 128 + blk] = h2u(__builtin_amdgcn_cvt_pkrtz(e0, e1));
}

// ---- kernel 2: one DRO solve per block; f16 dot2 matvecs, fp32 exact projection ----
__global__ __launch_bounds__(256, 1)
void dro_kernel(const __fp16* __restrict__ ep_row, const unsigned* __restrict__ ep_cp,
                const float* __restrict__ yhat_g, float* __restrict__ z_out,
                const float* __restrict__ d_delta, const float* __restrict__ d_gamma) {
    __shared__ float gzp[2][4][NY];              // cross-wave partials, dbuf
    __shared__ __align__(16) float red[2][8];    // cross-wave {S1,S2}, dbuf

    const int tid  = threadIdx.x;
    const int lane = tid & 63;
    const int wid  = tid >> 6;
    const int blk  = blockIdx.x;

    // row layout: thread tid holds ep[tid][0..127] as 64 packed half2 (64 VGPRs)
    unsigned rA[64];
    {
        const uint4* p = (const uint4*)(ep_row + tid * NY);
#pragma unroll
        for (int q = 0; q < 16; ++q) {
            const uint4 v = p[q];
            rA[4 * q + 0] = v.x; rA[4 * q + 1] = v.y;
            rA[4 * q + 2] = v.z; rA[4 * q + 3] = v.w;
        }
    }

    // col layout: lane holds (ep[tbase+2i][j], ep[tbase+2i+1][j]) for j0,j1 (64 VGPRs)
    const int j0    = lane << 1;
    const int tbase = wid << 6;
    unsigned rb0[32], rb1[32];
    {
        const unsigned* c0 = ep_cp + j0 * 128 + (tbase >> 1);
        const unsigned* c1 = ep_cp + (j0 + 1) * 128 + (tbase >> 1);
#pragma unroll
        for (int i = 0; i < 32; ++i) { rb0[i] = c0[i]; rb1[i] = c1[i]; }
    }

    const float yh0 = yhat_g[blk * NY + j0];
    const float yh1 = yhat_g[blk * NY + j0 + 1];

    float z0 = 1.0f / 128.0f, z1 = 1.0f / 128.0f;
    float act0 = 1.f, act1 = 1.f;    // Michelot warm-start support

    const float delta = d_delta[0];
    const float gamma = d_gamma[0];
    float c = 0.f, eta = 0.f, lam = 0.1f;
    int buf = 0;

    for (int k = 0; k < NITER; ++k) {
        const float lr = 0.05f * __builtin_amdgcn_rsqf(1.0f + (float)k);

        // ---- phase A: r_t = ep[t,:].z - c ; z packed h2, broadcast via readlane ----
        const unsigned zp = h2u(__builtin_amdgcn_cvt_pkrtz(z0, z1));
        float acA = 0.f, acB = 0.f;
#pragma unroll
        for (int q = 0; q < 64; q += 2) {
            acA = dot2u(rA[q],     rlu(zp, q),     acA);
            acB = dot2u(rA[q + 1], rlu(zp, q + 1), acB);
        }
        const float r  = acA + acB - c;
        const float q2 = r * r - eta;
        const float aa = -lam;
        const float st = (q2 > aa) ? 1.0f : ((q2 == aa) ? 0.5f : 0.0f);
        const float wv = st * r;

        // ---- S1/S2 reduction ----
        float s1 = st, s2 = wv;
        wave_sum2(s1, s2);
        if (lane == 0) { red[buf][wid * 2] = s1; red[buf][wid * 2 + 1] = s2; }

        // ---- pack w pairs: even lane 2i holds (w[tbase+2i], w[tbase+2i+1]) ----
        const float wpart = __int_as_float(
            __builtin_amdgcn_update_dpp(0, __float_as_int(wv), DPP_QUAD_X1, 0xf, 0xf, true));
        const unsigned wpk = h2u(__builtin_amdgcn_cvt_pkrtz(wv, wpart));

        // ---- phase B: per-wave partial gz over own 64 rows (32 packed pairs) ----
        float p0 = 0.f, p1 = 0.f;
#pragma unroll
        for (int i = 0; i < 32; ++i) {
            const unsigned wu = rlu(wpk, 2 * i);
            p0 = dot2u(rb0[i], wu, p0);
            p1 = dot2u(rb1[i], wu, p1);
        }
        *(float2*)&gzp[buf][wid][j0] = make_float2(p0, p1);

        __syncthreads();   // the ONE barrier: gzp[buf] + red[buf] visible

        // ---- all waves redundantly: scalar updates + z step + projection ----
        const float4 rd0 = *(const float4*)&red[buf][0];
        const float4 rd1 = *(const float4*)&red[buf][4];
        const float S1 = (rd0.x + rd0.z) + (rd1.x + rd1.z);
        const float S2 = (rd0.y + rd0.w) + (rd1.y + rd1.w);
        c   -= lr * (-(2.0f / 256.0f) * S2);
        eta -= lr * (1.0f - S1 * (1.0f / 256.0f));
        lam  = fmaxf(lam - lr * (delta - 1.0f + S1 * (1.0f / 256.0f)), 0.0f);

        const float2 g0v = *(const float2*)&gzp[buf][0][j0];
        const float2 g1v = *(const float2*)&gzp[buf][1][j0];
        const float2 g2v = *(const float2*)&gzp[buf][2][j0];
        const float2 g3v = *(const float2*)&gzp[buf][3][j0];
        const float g0 = (g0v.x + g1v.x) + (g2v.x + g3v.x);
        const float g1 = (g0v.y + g1v.y) + (g2v.y + g3v.y);
        const float v0 = z0 - lr * ((2.0f / 256.0f) * g0 - gamma * yh0);
        const float v1 = z1 - lr * ((2.0f / 256.0f) * g1 - gamma * yh1);

        // ---- Michelot projection (fp32, exact): warm start + ballot fixed point ----
        float theta = 0.f;
        for (int attempt = 0; attempt < 2; ++attempt) {
            for (int m = 0; m < 128; ++m) {
                float s  = act0 * v0 + act1 * v1;
                float cc = act0 + act1;
                wave_sum2(s, cc);
                theta = (s - 1.0f) * __builtin_amdgcn_rcpf(cc);
                const float n0 = (v0 > theta) ? act0 : 0.f;
                const float n1 = (v1 > theta) ? act1 : 0.f;
                const bool changed = (n0 != act0) || (n1 != act1);
                act0 = n0; act1 = n1;
                if (!__any(changed)) break;
            }
            const bool viol = ((act0 == 0.f) && (v0 > theta)) ||
                              ((act1 == 0.f) && (v1 > theta));
            if (!__any(viol)) break;
            act0 = 1.f; act1 = 1.f;
        }
        z0 = fmaxf(v0 - theta, 0.f);
        z1 = fmaxf(v1 - theta, 0.f);

        buf ^= 1;
    }

    if (wid == 0) *(float2*)&z_out[blk * NY + j0] = make_float2(z0, z1);
}

extern "C" void kernel_launch(void* const* d_in, const int* in_sizes, int n_in,
                              void* d_out, int out_size, void* d_ws, size_t ws_size,
                              hipStream_t stream) {
    const float* X       = (const float*)d_in[0];   // 256*64
    const float* Y       = (const float*)d_in[1];   // 256*128
    const float* W       = (const float*)d_in[2];   // 128*64
    const float* b       = (const float*)d_in[3];   // 128
    const float* d_delta = (const float*)d_in[4];   // 1
    const float* d_gamma = (const float*)d_in[5];   // 1

    float* z_out    = (float*)d_out;                // Z_star: 256*128
    float* yhat_out = z_out + T_OBS * NY;           // Y_hat:  256*128

    __fp16*   ep_row = (__fp16*)d_ws;                           // 64 KB
    unsigned* ep_cp  = (unsigned*)((char*)d_ws + 65536);        // 64 KB

    pred_kernel<<<T_OBS / 2, 128, 0, stream>>>(X, Y, W, b, yhat_out, ep_row, ep_cp);
    dro_kernel<<<T_OBS, 256, 0, stream>>>(ep_row, ep_cp, yhat_out, z_out, d_delta, d_gamma);
}

// Round 7
// 246.276 us; speedup vs baseline: 1.0254x; 1.0254x over previous
//
#include <hip/hip_runtime.h>
#include <math.h>

#define T_OBS 256
#define NY 128
#define NITER 150

typedef __fp16 half2_t __attribute__((ext_vector_type(2)));

// ---- gfx9/CDNA DPP wave64 reduction: row_shr 1,2,4,8 + bcast15 + bcast31 ----
#define DPP_ROW_SHR1 0x111
#define DPP_ROW_SHR2 0x112
#define DPP_ROW_SHR4 0x114
#define DPP_ROW_SHR8 0x118
#define DPP_BCAST15  0x142
#define DPP_BCAST31  0x143
#define DPP_QUAD_X1  0xB1   // quad_perm [1,0,3,2]

#define DPP_ADD_F32(x, ctrl) \
    (x) += __int_as_float(__builtin_amdgcn_update_dpp(0, __float_as_int(x), (ctrl), 0xf, 0xf, true))

__device__ __forceinline__ void wave_sum2(float& a, float& b) {
    DPP_ADD_F32(a, DPP_ROW_SHR1); DPP_ADD_F32(b, DPP_ROW_SHR1);
    DPP_ADD_F32(a, DPP_ROW_SHR2); DPP_ADD_F32(b, DPP_ROW_SHR2);
    DPP_ADD_F32(a, DPP_ROW_SHR4); DPP_ADD_F32(b, DPP_ROW_SHR4);
    DPP_ADD_F32(a, DPP_ROW_SHR8); DPP_ADD_F32(b, DPP_ROW_SHR8);
    DPP_ADD_F32(a, DPP_BCAST15);  DPP_ADD_F32(b, DPP_BCAST15);
    DPP_ADD_F32(a, DPP_BCAST31);  DPP_ADD_F32(b, DPP_BCAST31);
    a = __int_as_float(__builtin_amdgcn_readlane(__float_as_int(a), 63));
    b = __int_as_float(__builtin_amdgcn_readlane(__float_as_int(b), 63));
}

__device__ __forceinline__ unsigned rlu(unsigned x, int l) {
    return (unsigned)__builtin_amdgcn_readlane((int)x, l);
}
__device__ __forceinline__ unsigned h2u(half2_t h) {
    return __builtin_bit_cast(unsigned, h);
}
__device__ __forceinline__ half2_t u2h(unsigned u) {
    return __builtin_bit_cast(half2_t, u);
}
__device__ __forceinline__ float dot2u(unsigned a, unsigned b, float c) {
#if __has_builtin(__builtin_amdgcn_fdot2)
    return __builtin_amdgcn_fdot2(u2h(a), u2h(b), c, false);
#else
    half2_t ha = u2h(a), hb = u2h(b);
    return fmaf((float)ha.y, (float)hb.y, fmaf((float)ha.x, (float)hb.x, c));
#endif
}

// ---- kernel 1: Y_hat = X W^T + b ; ep = Y - Y_hat, emitted in two f16 layouts ----
__global__ __launch_bounds__(128)
void pred_kernel(const float* __restrict__ X, const float* __restrict__ Y,
                 const float* __restrict__ W, const float* __restrict__ bb,
                 float* __restrict__ yhat, __fp16* __restrict__ ep_row,
                 unsigned* __restrict__ ep_cp) {
    __shared__ float xrow[128];               // rows t0,t0+1 of X (contiguous)
    const int blk = blockIdx.x;               // 0..127
    const int j   = threadIdx.x;              // 0..127
    const int t0  = blk << 1;
    xrow[j] = X[t0 * 64 + j];
    __syncthreads();
    const float* wr = W + j * 64;
    float a0 = 0.f, a1 = 0.f;
#pragma unroll
    for (int x = 0; x < 64; ++x) {
        const float w = wr[x];
        a0 = fmaf(xrow[x],      w, a0);
        a1 = fmaf(xrow[64 + x], w, a1);
    }
    const float yh0 = a0 + bb[j];
    const float yh1 = a1 + bb[j];
    yhat[t0 * NY + j]       = yh0;
    yhat[(t0 + 1) * NY + j] = yh1;
    const float e0 = Y[t0 * NY + j] - yh0;
    const float e1 = Y[(t0 + 1) * NY + j] - yh1;
    ep_row[t0 * NY + j]       = (__fp16)e0;
    ep_row[(t0 + 1) * NY + j] = (__fp16)e1;
    // col-pair layout: ep_cp[j*128 + blk] = (ep[2blk][j], ep[2blk+1][j])
    ep_cp[j * 128 + blk] = h2u(__builtin_amdgcn_cvt_pkrtz(e0, e1));
}

// ---- kernel 2: one DRO solve per block; f16 dot2 matvecs, fp32 exact projection ----
// amdgpu_waves_per_eu(1,1): only 1 wave/SIMD can ever be resident (grid = 1
// block/CU), so let the allocator use the full 512-VGPR budget and keep both
// ep layouts register-resident instead of re-loading from L1/L2 every iter.
__global__ __attribute__((amdgpu_flat_work_group_size(256, 256),
                          amdgpu_waves_per_eu(1, 1)))
void dro_kernel(const __fp16* __restrict__ ep_row, const unsigned* __restrict__ ep_cp,
                const float* __restrict__ yhat_g, float* __restrict__ z_out,
                const float* __restrict__ d_delta, const float* __restrict__ d_gamma) {
    __shared__ float gzp[2][4][NY];              // cross-wave partials, dbuf
    __shared__ __align__(16) float red[2][8];    // cross-wave {S1,S2}, dbuf

    const int tid  = threadIdx.x;
    const int lane = tid & 63;
    const int wid  = tid >> 6;
    const int blk  = blockIdx.x;

    // row layout: thread tid holds ep[tid][0..127] as 64 packed half2 (64 VGPRs)
    unsigned rA[64];
    {
        const uint4* p = (const uint4*)(ep_row + tid * NY);
#pragma unroll
        for (int q = 0; q < 16; ++q) {
            const uint4 v = p[q];
            rA[4 * q + 0] = v.x; rA[4 * q + 1] = v.y;
            rA[4 * q + 2] = v.z; rA[4 * q + 3] = v.w;
        }
    }

    // col layout: lane holds (ep[tbase+2i][j], ep[tbase+2i+1][j]) for j0,j1 (64 VGPRs)
    const int j0    = lane << 1;
    const int tbase = wid << 6;
    unsigned rb0[32], rb1[32];
    {
        const unsigned* c0 = ep_cp + j0 * 128 + (tbase >> 1);
        const unsigned* c1 = ep_cp + (j0 + 1) * 128 + (tbase >> 1);
#pragma unroll
        for (int i = 0; i < 32; ++i) { rb0[i] = c0[i]; rb1[i] = c1[i]; }
    }

    const float yh0 = yhat_g[blk * NY + j0];
    const float yh1 = yhat_g[blk * NY + j0 + 1];

    float z0 = 1.0f / 128.0f, z1 = 1.0f / 128.0f;
    float act0 = 1.f, act1 = 1.f;    // Michelot warm-start support

    const float delta = d_delta[0];
    const float gamma = d_gamma[0];
    float c = 0.f, eta = 0.f, lam = 0.1f;
    int buf = 0;

    for (int k = 0; k < NITER; ++k) {
        const float lr = 0.05f * __builtin_amdgcn_rsqf(1.0f + (float)k);

        // ---- phase A: r_t = ep[t,:].z ; 4 independent dot2 chains ----
        const unsigned zp = h2u(__builtin_amdgcn_cvt_pkrtz(z0, z1));
        float ac0 = 0.f, ac1 = 0.f, ac2 = 0.f, ac3 = 0.f;
#pragma unroll
        for (int q = 0; q < 64; q += 4) {
            ac0 = dot2u(rA[q],     rlu(zp, q),     ac0);
            ac1 = dot2u(rA[q + 1], rlu(zp, q + 1), ac1);
            ac2 = dot2u(rA[q + 2], rlu(zp, q + 2), ac2);
            ac3 = dot2u(rA[q + 3], rlu(zp, q + 3), ac3);
        }
        const float r  = ((ac0 + ac1) + (ac2 + ac3)) - c;
        const float q2 = r * r - eta;
        const float aa = -lam;
        const float st = (q2 > aa) ? 1.0f : ((q2 == aa) ? 0.5f : 0.0f);
        const float wv = st * r;

        // ---- S1/S2 reduction ----
        float s1 = st, s2 = wv;
        wave_sum2(s1, s2);
        if (lane == 0) { red[buf][wid * 2] = s1; red[buf][wid * 2 + 1] = s2; }

        // ---- pack w pairs: even lane 2i holds (w[tbase+2i], w[tbase+2i+1]) ----
        const float wpart = __int_as_float(
            __builtin_amdgcn_update_dpp(0, __float_as_int(wv), DPP_QUAD_X1, 0xf, 0xf, true));
        const unsigned wpk = h2u(__builtin_amdgcn_cvt_pkrtz(wv, wpart));

        // ---- phase B: per-wave partial gz; 4 independent dot2 chains ----
        float p0a = 0.f, p0b = 0.f, p1a = 0.f, p1b = 0.f;
#pragma unroll
        for (int i = 0; i < 32; i += 2) {
            const unsigned wua = rlu(wpk, 2 * i);
            const unsigned wub = rlu(wpk, 2 * i + 2);
            p0a = dot2u(rb0[i],     wua, p0a);
            p1a = dot2u(rb1[i],     wua, p1a);
            p0b = dot2u(rb0[i + 1], wub, p0b);
            p1b = dot2u(rb1[i + 1], wub, p1b);
        }
        *(float2*)&gzp[buf][wid][j0] = make_float2(p0a + p0b, p1a + p1b);

        __syncthreads();   // the ONE barrier: gzp[buf] + red[buf] visible

        // ---- all waves redundantly: scalar updates + z step + projection ----
        const float4 rd0 = *(const float4*)&red[buf][0];
        const float4 rd1 = *(const float4*)&red[buf][4];
        const float S1 = (rd0.x + rd0.z) + (rd1.x + rd1.z);
        const float S2 = (rd0.y + rd0.w) + (rd1.y + rd1.w);
        c   -= lr * (-(2.0f / 256.0f) * S2);
        eta -= lr * (1.0f - S1 * (1.0f / 256.0f));
        lam  = fmaxf(lam - lr * (delta - 1.0f + S1 * (1.0f / 256.0f)), 0.0f);

        const float2 g0v = *(const float2*)&gzp[buf][0][j0];
        const float2 g1v = *(const float2*)&gzp[buf][1][j0];
        const float2 g2v = *(const float2*)&gzp[buf][2][j0];
        const float2 g3v = *(const float2*)&gzp[buf][3][j0];
        const float g0 = (g0v.x + g1v.x) + (g2v.x + g3v.x);
        const float g1 = (g0v.y + g1v.y) + (g2v.y + g3v.y);
        const float v0 = z0 - lr * ((2.0f / 256.0f) * g0 - gamma * yh0);
        const float v1 = z1 - lr * ((2.0f / 256.0f) * g1 - gamma * yh1);

        // ---- Michelot projection (fp32, exact): warm start + ballot fixed point ----
        float theta = 0.f;
        for (int attempt = 0; attempt < 2; ++attempt) {
            for (int m = 0; m < 128; ++m) {
                float s  = act0 * v0 + act1 * v1;
                float cc = act0 + act1;
                wave_sum2(s, cc);
                theta = (s - 1.0f) * __builtin_amdgcn_rcpf(cc);
                const float n0 = (v0 > theta) ? act0 : 0.f;
                const float n1 = (v1 > theta) ? act1 : 0.f;
                const bool changed = (n0 != act0) || (n1 != act1);
                act0 = n0; act1 = n1;
                if (!__any(changed)) break;
            }
            const bool viol = ((act0 == 0.f) && (v0 > theta)) ||
                              ((act1 == 0.f) && (v1 > theta));
            if (!__any(viol)) break;
            act0 = 1.f; act1 = 1.f;
        }
        z0 = fmaxf(v0 - theta, 0.f);
        z1 = fmaxf(v1 - theta, 0.f);

        buf ^= 1;
    }

    if (wid == 0) *(float2*)&z_out[blk * NY + j0] = make_float2(z0, z1);
}

extern "C" void kernel_launch(void* const* d_in, const int* in_sizes, int n_in,
                              void* d_out, int out_size, void* d_ws, size_t ws_size,
                              hipStream_t stream) {
    const float* X       = (const float*)d_in[0];   // 256*64
    const float* Y       = (const float*)d_in[1];   // 256*128
    const float* W       = (const float*)d_in[2];   // 128*64
    const float* b       = (const float*)d_in[3];   // 128
    const float* d_delta = (const float*)d_in[4];   // 1
    const float* d_gamma = (const float*)d_in[5];   // 1

    float* z_out    = (float*)d_out;                // Z_star: 256*128
    float* yhat_out = z_out + T_OBS * NY;           // Y_hat:  256*128

    __fp16*   ep_row = (__fp16*)d_ws;                           // 64 KB
    unsigned* ep_cp  = (unsigned*)((char*)d_ws + 65536);        // 64 KB

    pred_kernel<<<T_OBS / 2, 128, 0, stream>>>(X, Y, W, b, yhat_out, ep_row, ep_cp);
    dro_kernel<<<T_OBS, 256, 0, stream>>>(ep_row, ep_cp, yhat_out, z_out, d_delta, d_gamma);
}

// Round 8
// 243.460 us; speedup vs baseline: 1.0372x; 1.0116x over previous
//
#include <hip/hip_runtime.h>
#include <math.h>

#define T_OBS 256
#define NY 128
#define NITER 150

typedef __fp16 half2_t __attribute__((ext_vector_type(2)));

// ---- gfx9/CDNA DPP wave64 reduction: row_shr 1,2,4,8 + bcast15 + bcast31 ----
#define DPP_ROW_SHR1 0x111
#define DPP_ROW_SHR2 0x112
#define DPP_ROW_SHR4 0x114
#define DPP_ROW_SHR8 0x118
#define DPP_BCAST15  0x142
#define DPP_BCAST31  0x143
#define DPP_QUAD_X1  0xB1   // quad_perm [1,0,3,2]

#define DPP_ADD_F32(x, ctrl) \
    (x) += __int_as_float(__builtin_amdgcn_update_dpp(0, __float_as_int(x), (ctrl), 0xf, 0xf, true))

__device__ __forceinline__ void wave_sum2(float& a, float& b) {
    DPP_ADD_F32(a, DPP_ROW_SHR1); DPP_ADD_F32(b, DPP_ROW_SHR1);
    DPP_ADD_F32(a, DPP_ROW_SHR2); DPP_ADD_F32(b, DPP_ROW_SHR2);
    DPP_ADD_F32(a, DPP_ROW_SHR4); DPP_ADD_F32(b, DPP_ROW_SHR4);
    DPP_ADD_F32(a, DPP_ROW_SHR8); DPP_ADD_F32(b, DPP_ROW_SHR8);
    DPP_ADD_F32(a, DPP_BCAST15);  DPP_ADD_F32(b, DPP_BCAST15);
    DPP_ADD_F32(a, DPP_BCAST31);  DPP_ADD_F32(b, DPP_BCAST31);
    a = __int_as_float(__builtin_amdgcn_readlane(__float_as_int(a), 63));
    b = __int_as_float(__builtin_amdgcn_readlane(__float_as_int(b), 63));
}

__device__ __forceinline__ unsigned rlu(unsigned x, int l) {
    return (unsigned)__builtin_amdgcn_readlane((int)x, l);
}
__device__ __forceinline__ unsigned h2u(half2_t h) {
    return __builtin_bit_cast(unsigned, h);
}
__device__ __forceinline__ half2_t u2h(unsigned u) {
    return __builtin_bit_cast(half2_t, u);
}
__device__ __forceinline__ float dot2u(unsigned a, unsigned b, float c) {
#if __has_builtin(__builtin_amdgcn_fdot2)
    return __builtin_amdgcn_fdot2(u2h(a), u2h(b), c, false);
#else
    half2_t ha = u2h(a), hb = u2h(b);
    return fmaf((float)ha.y, (float)hb.y, fmaf((float)ha.x, (float)hb.x, c));
#endif
}
// Residency pin: breaks value<->memory identity so the compiler cannot
// rematerialize the load inside the loop; the value must stay in a VGPR.
#define PIN(x) asm volatile("" : "+v"(x))

// ---- kernel 1: Y_hat = X W^T + b ; ep = Y - Y_hat, emitted in two f16 layouts ----
__global__ __launch_bounds__(128)
void pred_kernel(const float* __restrict__ X, const float* __restrict__ Y,
                 const float* __restrict__ W, const float* __restrict__ bb,
                 float* __restrict__ yhat, __fp16* __restrict__ ep_row,
                 unsigned* __restrict__ ep_cp) {
    __shared__ float xrow[128];               // rows t0,t0+1 of X (contiguous)
    const int blk = blockIdx.x;               // 0..127
    const int j   = threadIdx.x;              // 0..127
    const int t0  = blk << 1;
    xrow[j] = X[t0 * 64 + j];
    __syncthreads();
    const float* wr = W + j * 64;
    float a0 = 0.f, a1 = 0.f;
#pragma unroll
    for (int x = 0; x < 64; ++x) {
        const float w = wr[x];
        a0 = fmaf(xrow[x],      w, a0);
        a1 = fmaf(xrow[64 + x], w, a1);
    }
    const float yh0 = a0 + bb[j];
    const float yh1 = a1 + bb[j];
    yhat[t0 * NY + j]       = yh0;
    yhat[(t0 + 1) * NY + j] = yh1;
    const float e0 = Y[t0 * NY + j] - yh0;
    const float e1 = Y[(t0 + 1) * NY + j] - yh1;
    ep_row[t0 * NY + j]       = (__fp16)e0;
    ep_row[(t0 + 1) * NY + j] = (__fp16)e1;
    // col-pair layout: ep_cp[j*128 + blk] = (ep[2blk][j], ep[2blk+1][j])
    ep_cp[j * 128 + blk] = h2u(__builtin_amdgcn_cvt_pkrtz(e0, e1));
}

// ---- kernel 2: one DRO solve per block; f16 dot2 matvecs, fp32 exact projection ----
// waves_per_eu(1,1): grid = 1 block/CU so only 1 wave/SIMD can be resident;
// give the allocator the full VGPR budget. PIN() forces ep residency.
__global__ __attribute__((amdgpu_flat_work_group_size(256, 256),
                          amdgpu_waves_per_eu(1, 1)))
void dro_kernel(const __fp16* __restrict__ ep_row, const unsigned* __restrict__ ep_cp,
                const float* __restrict__ yhat_g, float* __restrict__ z_out,
                const float* __restrict__ d_delta, const float* __restrict__ d_gamma) {
    __shared__ float gzp[2][4][NY];              // cross-wave partials, dbuf
    __shared__ __align__(16) float red[2][8];    // cross-wave {S1,S2}, dbuf

    const int tid  = threadIdx.x;
    const int lane = tid & 63;
    const int wid  = tid >> 6;
    const int blk  = blockIdx.x;

    // row layout: thread tid holds ep[tid][0..127] as 64 packed half2 (64 VGPRs)
    unsigned rA[64];
    {
        const uint4* p = (const uint4*)(ep_row + tid * NY);
#pragma unroll
        for (int q = 0; q < 16; ++q) {
            const uint4 v = p[q];
            rA[4 * q + 0] = v.x; rA[4 * q + 1] = v.y;
            rA[4 * q + 2] = v.z; rA[4 * q + 3] = v.w;
        }
    }

    // col layout: lane holds (ep[tbase+2i][j], ep[tbase+2i+1][j]) for j0,j1 (64 VGPRs)
    const int j0    = lane << 1;
    const int tbase = wid << 6;
    unsigned rb0[32], rb1[32];
    {
        const uint4* c0 = (const uint4*)(ep_cp + j0 * 128 + (tbase >> 1));
        const uint4* c1 = (const uint4*)(ep_cp + (j0 + 1) * 128 + (tbase >> 1));
#pragma unroll
        for (int i = 0; i < 8; ++i) {
            const uint4 v0 = c0[i], v1 = c1[i];
            rb0[4 * i + 0] = v0.x; rb0[4 * i + 1] = v0.y;
            rb0[4 * i + 2] = v0.z; rb0[4 * i + 3] = v0.w;
            rb1[4 * i + 0] = v1.x; rb1[4 * i + 1] = v1.y;
            rb1[4 * i + 2] = v1.z; rb1[4 * i + 3] = v1.w;
        }
    }

    // pin everything resident
#pragma unroll
    for (int q = 0; q < 64; ++q) PIN(rA[q]);
#pragma unroll
    for (int i = 0; i < 32; ++i) { PIN(rb0[i]); PIN(rb1[i]); }

    const float yh0 = yhat_g[blk * NY + j0];
    const float yh1 = yhat_g[blk * NY + j0 + 1];

    float z0 = 1.0f / 128.0f, z1 = 1.0f / 128.0f;
    float act0 = 1.f, act1 = 1.f;    // Michelot warm-start support

    const float delta = d_delta[0];
    const float gamma = d_gamma[0];
    float c = 0.f, eta = 0.f, lam = 0.1f;
    int buf = 0;

    for (int k = 0; k < NITER; ++k) {
        const float lr = 0.05f * __builtin_amdgcn_rsqf(1.0f + (float)k);

        // ---- phase A: r_t = ep[t,:].z ; 4 independent dot2 chains ----
        const unsigned zp = h2u(__builtin_amdgcn_cvt_pkrtz(z0, z1));
        float ac0 = 0.f, ac1 = 0.f, ac2 = 0.f, ac3 = 0.f;
#pragma unroll
        for (int q = 0; q < 64; q += 4) {
            ac0 = dot2u(rA[q],     rlu(zp, q),     ac0);
            ac1 = dot2u(rA[q + 1], rlu(zp, q + 1), ac1);
            ac2 = dot2u(rA[q + 2], rlu(zp, q + 2), ac2);
            ac3 = dot2u(rA[q + 3], rlu(zp, q + 3), ac3);
        }
        const float r  = ((ac0 + ac1) + (ac2 + ac3)) - c;
        const float q2 = r * r - eta;
        const float aa = -lam;
        const float st = (q2 > aa) ? 1.0f : ((q2 == aa) ? 0.5f : 0.0f);
        const float wv = st * r;

        // ---- S1/S2 reduction ----
        float s1 = st, s2 = wv;
        wave_sum2(s1, s2);
        if (lane == 0) { red[buf][wid * 2] = s1; red[buf][wid * 2 + 1] = s2; }

        // ---- pack w pairs: even lane 2i holds (w[tbase+2i], w[tbase+2i+1]) ----
        const float wpart = __int_as_float(
            __builtin_amdgcn_update_dpp(0, __float_as_int(wv), DPP_QUAD_X1, 0xf, 0xf, true));
        const unsigned wpk = h2u(__builtin_amdgcn_cvt_pkrtz(wv, wpart));

        // ---- phase B: per-wave partial gz; 4 independent dot2 chains ----
        float p0a = 0.f, p0b = 0.f, p1a = 0.f, p1b = 0.f;
#pragma unroll
        for (int i = 0; i < 32; i += 2) {
            const unsigned wua = rlu(wpk, 2 * i);
            const unsigned wub = rlu(wpk, 2 * i + 2);
            p0a = dot2u(rb0[i],     wua, p0a);
            p1a = dot2u(rb1[i],     wua, p1a);
            p0b = dot2u(rb0[i + 1], wub, p0b);
            p1b = dot2u(rb1[i + 1], wub, p1b);
        }
        *(float2*)&gzp[buf][wid][j0] = make_float2(p0a + p0b, p1a + p1b);

        __syncthreads();   // the ONE barrier: gzp[buf] + red[buf] visible

        // ---- all waves redundantly: scalar updates + z step + projection ----
        const float4 rd0 = *(const float4*)&red[buf][0];
        const float4 rd1 = *(const float4*)&red[buf][4];
        const float S1 = (rd0.x + rd0.z) + (rd1.x + rd1.z);
        const float S2 = (rd0.y + rd0.w) + (rd1.y + rd1.w);
        c   -= lr * (-(2.0f / 256.0f) * S2);
        eta -= lr * (1.0f - S1 * (1.0f / 256.0f));
        lam  = fmaxf(lam - lr * (delta - 1.0f + S1 * (1.0f / 256.0f)), 0.0f);

        const float2 g0v = *(const float2*)&gzp[buf][0][j0];
        const float2 g1v = *(const float2*)&gzp[buf][1][j0];
        const float2 g2v = *(const float2*)&gzp[buf][2][j0];
        const float2 g3v = *(const float2*)&gzp[buf][3][j0];
        const float g0 = (g0v.x + g1v.x) + (g2v.x + g3v.x);
        const float g1 = (g0v.y + g1v.y) + (g2v.y + g3v.y);
        const float v0 = z0 - lr * ((2.0f / 256.0f) * g0 - gamma * yh0);
        const float v1 = z1 - lr * ((2.0f / 256.0f) * g1 - gamma * yh1);

        // ---- Michelot projection (fp32, exact): warm start + ballot fixed point ----
        float theta = 0.f;
        for (int attempt = 0; attempt < 2; ++attempt) {
            for (int m = 0; m < 128; ++m) {
                float s  = act0 * v0 + act1 * v1;
                float cc = act0 + act1;
                wave_sum2(s, cc);
                theta = (s - 1.0f) * __builtin_amdgcn_rcpf(cc);
                const float n0 = (v0 > theta) ? act0 : 0.f;
                const float n1 = (v1 > theta) ? act1 : 0.f;
                const bool changed = (n0 != act0) || (n1 != act1);
                act0 = n0; act1 = n1;
                if (!__any(changed)) break;
            }
            const bool viol = ((act0 == 0.f) && (v0 > theta)) ||
                              ((act1 == 0.f) && (v1 > theta));
            if (!__any(viol)) break;
            act0 = 1.f; act1 = 1.f;
        }
        z0 = fmaxf(v0 - theta, 0.f);
        z1 = fmaxf(v1 - theta, 0.f);

        buf ^= 1;
    }

    if (wid == 0) *(float2*)&z_out[blk * NY + j0] = make_float2(z0, z1);
}

extern "C" void kernel_launch(void* const* d_in, const int* in_sizes, int n_in,
                              void* d_out, int out_size, void* d_ws, size_t ws_size,
                              hipStream_t stream) {
    const float* X       = (const float*)d_in[0];   // 256*64
    const float* Y       = (const float*)d_in[1];   // 256*128
    const float* W       = (const float*)d_in[2];   // 128*64
    const float* b       = (const float*)d_in[3];   // 128
    const float* d_delta = (const float*)d_in[4];   // 1
    const float* d_gamma = (const float*)d_in[5];   // 1

    float* z_out    = (float*)d_out;                // Z_star: 256*128
    float* yhat_out = z_out + T_OBS * NY;           // Y_hat:  256*128

    __fp16*   ep_row = (__fp16*)d_ws;                           // 64 KB
    unsigned* ep_cp  = (unsigned*)((char*)d_ws + 65536);        // 64 KB

    pred_kernel<<<T_OBS / 2, 128, 0, stream>>>(X, Y, W, b, yhat_out, ep_row, ep_cp);
    dro_kernel<<<T_OBS, 256, 0, stream>>>(ep_row, ep_cp, yhat_out, z_out, d_delta, d_gamma);
}